// Round 1
// baseline (441.666 us; speedup 1.0000x reference)
//
#include <hip/hip_runtime.h>
#include <math.h>

#define N_NODES 100000
#define N_EDGES 600000
#define DIM 128
#define LN_EPS 1e-5f
#define LDA 136  // padded LDS row stride in bf16 elements (128 + 8 -> 16B-aligned rows, conflict-light)

typedef __bf16 bf16x8 __attribute__((ext_vector_type(8)));
typedef __bf16 bf16x4 __attribute__((ext_vector_type(4)));
typedef float f32x4 __attribute__((ext_vector_type(4)));

// ---------------- weight convert: f32 -> bf16 (once per call, tiny) ----------------
__global__ void wconv_kernel(const float* __restrict__ Wself,
                             const float* __restrict__ Wneigh,
                             const float* __restrict__ Wgate,
                             __bf16* __restrict__ wself_bf,
                             __bf16* __restrict__ wneigh_bf,
                             __bf16* __restrict__ wgh_bf,
                             __bf16* __restrict__ wgm_bf) {
  int i = blockIdx.x * 256 + threadIdx.x;  // 65536 total
  if (i < 16384) {
    wself_bf[i] = (__bf16)Wself[i];
  } else if (i < 32768) {
    int j = i - 16384;
    wneigh_bf[j] = (__bf16)Wneigh[j];
  } else {
    int j = i - 32768;           // over [128][256] row-major
    int d = j >> 8, k = j & 255;
    float v = Wgate[j];
    if (k < 128) wgh_bf[d * 128 + k] = (__bf16)v;
    else         wgm_bf[d * 128 + (k - 128)] = (__bf16)v;
  }
}

// ---------------- edge scatter: nsum[dst] += h[src], counts[dst]++ ----------------
__global__ void scatter_kernel(const float* __restrict__ h,
                               const int* __restrict__ esrc,
                               const int* __restrict__ edst,
                               float* __restrict__ nsum,
                               int* __restrict__ counts) {
  int e = blockIdx.x * 2 + (threadIdx.x >> 7);
  if (e >= N_EDGES) return;
  int t = threadIdx.x & 127;
  int s = esrc[e], d = edst[e];
  float v = h[(size_t)s * DIM + t];
  atomicAdd(&nsum[(size_t)d * DIM + t], v);
  if (t == 0) atomicAdd(&counts[d], 1);
}

// ---------------- fused node kernel: 64 nodes/block, 4 waves, MFMA bf16 ----------------
__global__ __launch_bounds__(256)
void node_kernel(const float* __restrict__ h,
                 const float* nsum,          // aliases out (d_out reused as accumulator)
                 const int* __restrict__ counts,
                 const __bf16* __restrict__ wself_bf,
                 const __bf16* __restrict__ wneigh_bf,
                 const __bf16* __restrict__ wgh_bf,
                 const __bf16* __restrict__ wgm_bf,
                 const float* __restrict__ b_self,
                 const float* __restrict__ b_neigh,
                 const float* __restrict__ b_gate,
                 const float* __restrict__ ln_g,
                 const float* __restrict__ ln_b,
                 float* out) {
  __shared__ __bf16 Ah[64 * LDA];    // h tile (bf16)
  __shared__ __bf16 Am[64 * LDA];    // neigh_mean tile, later m tile
  __shared__ __bf16 Wsh[128 * LDA];  // current weight matrix [d][k], k-contiguous
  __shared__ float csh[64];

  const int tid = threadIdx.x;
  const int lane = tid & 63;
  const int wave = tid >> 6;
  const int node0 = blockIdx.x * 64;

  if (tid < 64) {
    int n = node0 + tid;
    csh[tid] = (n < N_NODES) ? (float)counts[n] : 0.0f;
  }
  __syncthreads();

  auto stage_w = [&](const __bf16* __restrict__ W) {
    // 128x128 bf16 = 2048 chunks of 8 elems (16B)
    for (int c = tid; c < 2048; c += 256) {
      int row = c >> 4, col8 = c & 15;
      bf16x8 v = *reinterpret_cast<const bf16x8*>(W + row * 128 + col8 * 8);
      *reinterpret_cast<bf16x8*>(&Wsh[row * LDA + col8 * 8]) = v;
    }
  };

  // stage h -> Ah, mean = nsum/max(cnt,1) -> Am (both bf16); 2048 chunks of 4 f32
  for (int c = tid; c < 2048; c += 256) {
    int row = c >> 5, col4 = c & 31;
    int n = node0 + row;
    float4 v = make_float4(0.f, 0.f, 0.f, 0.f);
    float4 s = v;
    if (n < N_NODES) {
      v = *reinterpret_cast<const float4*>(h + (size_t)n * DIM + col4 * 4);
      s = *reinterpret_cast<const float4*>(nsum + (size_t)n * DIM + col4 * 4);
    }
    float inv = 1.0f / fmaxf(csh[row], 1.0f);
    bf16x4 hv, mv;
    hv[0] = (__bf16)v.x; hv[1] = (__bf16)v.y; hv[2] = (__bf16)v.z; hv[3] = (__bf16)v.w;
    mv[0] = (__bf16)(s.x * inv); mv[1] = (__bf16)(s.y * inv);
    mv[2] = (__bf16)(s.z * inv); mv[3] = (__bf16)(s.w * inv);
    *reinterpret_cast<bf16x4*>(&Ah[row * LDA + col4 * 4]) = hv;
    *reinterpret_cast<bf16x4*>(&Am[row * LDA + col4 * 4]) = mv;
  }
  stage_w(wself_bf);
  __syncthreads();

  const int col = lane & 15;
  const int kb = (lane >> 4) * 8;
  const int arow = wave * 16 + col;                 // A row this lane feeds
  const int rbase = wave * 16 + ((lane >> 4) << 2); // local node for acc reg r=0

  auto gemm = [&](const __bf16* Abuf, f32x4* acc) {
#pragma unroll
    for (int k0 = 0; k0 < 128; k0 += 32) {
      bf16x8 a = *reinterpret_cast<const bf16x8*>(Abuf + arow * LDA + k0 + kb);
#pragma unroll
      for (int nb = 0; nb < 8; ++nb) {
        bf16x8 b = *reinterpret_cast<const bf16x8*>(&Wsh[(nb * 16 + col) * LDA + k0 + kb]);
        acc[nb] = __builtin_amdgcn_mfma_f32_16x16x32_bf16(a, b, acc[nb], 0, 0, 0);
      }
    }
  };

  f32x4 macc[8];
#pragma unroll
  for (int i = 0; i < 8; ++i) macc[i] = (f32x4){0.f, 0.f, 0.f, 0.f};
  gemm(Ah, macc);  // hs = h @ Wself^T

  __syncthreads();
  stage_w(wneigh_bf);
  __syncthreads();

  f32x4 nacc[8];
#pragma unroll
  for (int i = 0; i < 8; ++i) nacc[i] = (f32x4){0.f, 0.f, 0.f, 0.f};
  gemm(Am, nacc);  // hn = mean @ Wneigh^T

  // m = hs + b_self + has_pred * (hn + b_neigh)
  float hp[4];
#pragma unroll
  for (int r = 0; r < 4; ++r) hp[r] = (csh[rbase + r] > 0.f) ? 1.f : 0.f;
#pragma unroll
  for (int nb = 0; nb < 8; ++nb) {
    int d = nb * 16 + col;
    float bs = b_self[d], bn = b_neigh[d];
#pragma unroll
    for (int r = 0; r < 4; ++r)
      macc[nb][r] = macc[nb][r] + bs + hp[r] * (nacc[nb][r] + bn);
  }
  // write m (bf16) into Am — each wave touches only its own 16 rows
#pragma unroll
  for (int nb = 0; nb < 8; ++nb)
#pragma unroll
    for (int r = 0; r < 4; ++r)
      Am[(rbase + r) * LDA + nb * 16 + col] = (__bf16)macc[nb][r];

  __syncthreads();
  stage_w(wgh_bf);
  __syncthreads();

  f32x4 gacc[8];
#pragma unroll
  for (int i = 0; i < 8; ++i) gacc[i] = (f32x4){0.f, 0.f, 0.f, 0.f};
  gemm(Ah, gacc);  // gate += h @ Wg_h^T

  __syncthreads();
  stage_w(wgm_bf);
  __syncthreads();

  gemm(Am, gacc);  // gate += m @ Wg_m^T

  // epilogue: sigmoid gate, blend, LayerNorm, relu
  float vv[8][4];
  float s1[4] = {0.f, 0.f, 0.f, 0.f}, s2[4] = {0.f, 0.f, 0.f, 0.f};
#pragma unroll
  for (int nb = 0; nb < 8; ++nb) {
    int d = nb * 16 + col;
    float bg = b_gate[d];
#pragma unroll
    for (int r = 0; r < 4; ++r) {
      int n = node0 + rbase + r;
      float hval = 0.f;
      if (n < N_NODES) hval = h[(size_t)n * DIM + d];
      float g = 1.0f / (1.0f + __expf(-(gacc[nb][r] + bg)));
      float v = g * macc[nb][r] + (1.0f - g) * hval;
      vv[nb][r] = v;
      s1[r] += v;
      s2[r] += v * v;
    }
  }
#pragma unroll
  for (int off = 1; off < 16; off <<= 1) {
#pragma unroll
    for (int r = 0; r < 4; ++r) {
      s1[r] += __shfl_xor(s1[r], off);
      s2[r] += __shfl_xor(s2[r], off);
    }
  }
  float mu[4], rs[4];
#pragma unroll
  for (int r = 0; r < 4; ++r) {
    mu[r] = s1[r] * (1.0f / DIM);
    float var = s2[r] * (1.0f / DIM) - mu[r] * mu[r];
    rs[r] = rsqrtf(var + LN_EPS);
  }
#pragma unroll
  for (int nb = 0; nb < 8; ++nb) {
    int d = nb * 16 + col;
    float ga = ln_g[d], be = ln_b[d];
#pragma unroll
    for (int r = 0; r < 4; ++r) {
      int n = node0 + rbase + r;
      if (n < N_NODES) {
        float o = (vv[nb][r] - mu[r]) * rs[r] * ga + be;
        out[(size_t)n * DIM + d] = fmaxf(o, 0.f);
      }
    }
  }
}

extern "C" void kernel_launch(void* const* d_in, const int* in_sizes, int n_in,
                              void* d_out, int out_size, void* d_ws, size_t ws_size,
                              hipStream_t stream) {
  const float* h      = (const float*)d_in[0];
  const int*   esrc   = (const int*)d_in[1];
  const int*   edst   = (const int*)d_in[2];
  const float* Wself  = (const float*)d_in[3];
  const float* bself  = (const float*)d_in[4];
  const float* Wneigh = (const float*)d_in[5];
  const float* bneigh = (const float*)d_in[6];
  const float* Wgate  = (const float*)d_in[7];
  const float* bgate  = (const float*)d_in[8];
  const float* ln_g   = (const float*)d_in[9];
  const float* ln_b   = (const float*)d_in[10];
  float* out = (float*)d_out;

  char* ws = (char*)d_ws;
  int* counts = (int*)ws;                               // 400000 B
  __bf16* wself_bf  = (__bf16*)(ws + 400384);           // 32768 B each
  __bf16* wneigh_bf = wself_bf + 16384;
  __bf16* wgh_bf    = wneigh_bf + 16384;
  __bf16* wgm_bf    = wgh_bf + 16384;

  // d_out doubles as the neigh_sum accumulator; zero it + counts each call
  hipMemsetAsync(out, 0, (size_t)N_NODES * DIM * sizeof(float), stream);
  hipMemsetAsync(counts, 0, (size_t)N_NODES * sizeof(int), stream);

  wconv_kernel<<<256, 256, 0, stream>>>(Wself, Wneigh, Wgate,
                                        wself_bf, wneigh_bf, wgh_bf, wgm_bf);
  scatter_kernel<<<(N_EDGES + 1) / 2, 256, 0, stream>>>(h, esrc, edst, out, counts);
  node_kernel<<<(N_NODES + 63) / 64, 256, 0, stream>>>(
      h, out, counts, wself_bf, wneigh_bf, wgh_bf, wgm_bf,
      bself, bneigh, bgate, ln_g, ln_b, out);
}